// Round 2
// baseline (278.204 us; speedup 1.0000x reference)
//
#include <hip/hip_runtime.h>

#define SEQ  20
#define DK   64
#define SSTR 24      // score-row stride in floats (96 B, 16B-aligned)
#define WREG 512     // floats of LDS per wave: 480 scores + 20 rinv + pad

// Wave-synchronous LDS fence: lanes of a wave run in lockstep on CDNA, so a
// completed-write fence is enough -- no __syncthreads needed when each wave
// owns a private LDS region. The "memory" clobber stops compiler reordering.
__device__ __forceinline__ void wave_sync_lds() {
    __builtin_amdgcn_wave_barrier();
    asm volatile("s_waitcnt lgkmcnt(0)" ::: "memory");
    __builtin_amdgcn_wave_barrier();
}

__global__ __launch_bounds__(256, 4)
void fused_deatt_wave_kernel(const float* __restrict__ Qg,
                             const float* __restrict__ Kg,
                             const float* __restrict__ Vg,
                             const float* __restrict__ Mg,
                             float* __restrict__ deAtt,
                             float* __restrict__ attnOut,
                             int nbh)
{
    __shared__ float lds[4 * WREG];

    const int tid  = threadIdx.x;
    const int wv   = tid >> 6;
    const int lane = tid & 63;
    const int bh   = blockIdx.x * 4 + wv;
    if (bh >= nbh) return;           // wave-uniform; no block barriers exist

    float* sS    = lds + wv * WREG;  // [20][SSTR]
    float* sRinv = sS + SEQ * SSTR;  // [20]

    const size_t base = (size_t)bh * (SEQ * DK);
    const float4* gq = reinterpret_cast<const float4*>(Qg + base);
    const float4* gk = reinterpret_cast<const float4*>(Kg + base);
    const float4* gv = reinterpret_cast<const float4*>(Vg + base);
    const float*  m  = Mg + (size_t)bh * (SEQ * SEQ);

    // ---------- Phase B: exp-scores * mask; 4x2 register tiles, lanes 0..49
    if (lane < 50) {
        const int qg = lane / 10;          // 0..4  -> q rows 4qg..4qg+3
        const int kg = lane - qg * 10;     // 0..9  -> k cols 2kg, 2kg+1
        const int q0 = qg * 4, k0 = kg * 2;
        float a[4][2] = {};
        #pragma unroll 4
        for (int g = 0; g < 16; ++g) {
            const float4 ka = gk[(k0    ) * 16 + g];
            const float4 kb = gk[(k0 + 1) * 16 + g];
            #pragma unroll
            for (int i = 0; i < 4; ++i) {
                const float4 qa = gq[(q0 + i) * 16 + g];
                a[i][0] += qa.x*ka.x + qa.y*ka.y + qa.z*ka.z + qa.w*ka.w;
                a[i][1] += qa.x*kb.x + qa.y*kb.y + qa.z*kb.z + qa.w*kb.w;
            }
        }
        #pragma unroll
        for (int i = 0; i < 4; ++i) {
            const float2 mm = *reinterpret_cast<const float2*>(m + (q0 + i) * SEQ + k0);
            const float e0 = __expf(a[i][0] * 0.125f) * mm.x;
            const float e1 = __expf(a[i][1] * 0.125f) * mm.y;
            *reinterpret_cast<float2*>(sS + (q0 + i) * SSTR + k0) = make_float2(e0, e1);
        }
    }
    wave_sync_lds();

    // ---------- Phase C: row sums -> 1/(sum+eps); lanes 0..19
    if (lane < SEQ) {
        const float4* row = reinterpret_cast<const float4*>(sS + lane * SSTR);
        const float4 r0 = row[0], r1 = row[1], r2 = row[2], r3 = row[3], r4 = row[4];
        float s = r0.x + r0.y + r0.z + r0.w
                + r1.x + r1.y + r1.z + r1.w
                + r2.x + r2.y + r2.z + r2.w
                + r3.x + r3.y + r3.z + r3.w
                + r4.x + r4.y + r4.z + r4.w;
        sRinv[lane] = 1.0f / (s + 1e-8f);
    }
    wave_sync_lds();

    // ---------- Phase D: write normalized attn (100 float4 per bh)
    {
        float4* aout = reinterpret_cast<float4*>(attnOut + (size_t)bh * (SEQ * SEQ));
        #pragma unroll
        for (int r = 0; r < 2; ++r) {
            const int idx = lane + r * 64;
            if (idx < 100) {
                const int q  = idx / 5;          // 0..19
                const int g4 = idx - q * 5;      // 0..4
                const float4 s = *reinterpret_cast<const float4*>(sS + q * SSTR + g4 * 4);
                const float rv = sRinv[q];
                aout[idx] = make_float4(s.x * rv, s.y * rv, s.z * rv, s.w * rv);
            }
        }
    }

    // ---------- Phase E: deAtt = (attn + Md) @ V; all 64 lanes (qg, dg)
    {
        const int qg = lane >> 4;       // 0..3 -> q rows qg*5 .. qg*5+4
        const int dg = lane & 15;       // 0..15 -> output float4 column
        float rv[5];
        #pragma unroll
        for (int j = 0; j < 5; ++j) rv[j] = sRinv[qg * 5 + j];

        float4 acc[5];
        #pragma unroll
        for (int j = 0; j < 5; ++j) acc[j] = make_float4(0.f, 0.f, 0.f, 0.f);

        #pragma unroll
        for (int k4 = 0; k4 < 5; ++k4) {
            const int kb = k4 * 4;
            const float4 v0 = gv[(kb + 0) * 16 + dg];
            const float4 v1 = gv[(kb + 1) * 16 + dg];
            const float4 v2 = gv[(kb + 2) * 16 + dg];
            const float4 v3 = gv[(kb + 3) * 16 + dg];
            const float kf0 = (float)(kb + 0), kf1 = (float)(kb + 1);
            const float kf2 = (float)(kb + 2), kf3 = (float)(kb + 3);
            #pragma unroll
            for (int j = 0; j < 5; ++j) {
                const int q = qg * 5 + j;
                const float qf = (float)q;
                const float4 s = *reinterpret_cast<const float4*>(sS + q * SSTR + kb);
                // Md folded in: w = attn - |q-k|; fabs becomes an input modifier
                const float w0 = fmaf(s.x, rv[j], -fabsf(qf - kf0));
                const float w1 = fmaf(s.y, rv[j], -fabsf(qf - kf1));
                const float w2 = fmaf(s.z, rv[j], -fabsf(qf - kf2));
                const float w3 = fmaf(s.w, rv[j], -fabsf(qf - kf3));
                acc[j].x += w0 * v0.x + w1 * v1.x + w2 * v2.x + w3 * v3.x;
                acc[j].y += w0 * v0.y + w1 * v1.y + w2 * v2.y + w3 * v3.y;
                acc[j].z += w0 * v0.z + w1 * v1.z + w2 * v2.z + w3 * v3.z;
                acc[j].w += w0 * v0.w + w1 * v1.w + w2 * v2.w + w3 * v3.w;
            }
        }
        #pragma unroll
        for (int j = 0; j < 5; ++j) {
            const int q = qg * 5 + j;
            reinterpret_cast<float4*>(deAtt + base + q * DK)[dg] = acc[j];
        }
    }
}

extern "C" void kernel_launch(void* const* d_in, const int* in_sizes, int n_in,
                              void* d_out, int out_size, void* d_ws, size_t ws_size,
                              hipStream_t stream) {
    const float* Q = (const float*)d_in[0];
    const float* K = (const float*)d_in[1];
    const float* V = (const float*)d_in[2];
    const float* M = (const float*)d_in[3];
    float* out = (float*)d_out;

    const int nbh = in_sizes[0] / (SEQ * DK);        // B*H = 8192
    float* deAtt = out;                              // [nbh, SEQ, DK]
    float* attn  = out + (size_t)nbh * SEQ * DK;     // [nbh, SEQ, SEQ]

    const int blocks = (nbh + 3) / 4;
    fused_deatt_wave_kernel<<<blocks, 256, 0, stream>>>(Q, K, V, M, deAtt, attn, nbh);
}

// Round 3
// 194.679 us; speedup vs baseline: 1.4290x; 1.4290x over previous
//
#include <hip/hip_runtime.h>

#define SEQ  20
#define DK   64
#define SSTR 24      // floats per score row (96 B; f4-aligned since 96 = 6*16)
#define WREG 512     // per-wave LDS floats: 480 scores + 20 rinv + 12 pad = 2 KB

// Wave-synchronous LDS fence (lanes of a wave run in lockstep; each wave owns
// a private LDS region, so lgkmcnt(0) is a sufficient write->read fence).
__device__ __forceinline__ void wave_sync_lds() {
    __builtin_amdgcn_wave_barrier();
    asm volatile("s_waitcnt lgkmcnt(0)" ::: "memory");
    __builtin_amdgcn_wave_barrier();
}

__global__ __launch_bounds__(256)
void fused_deatt_v3(const float* __restrict__ Qg,
                    const float* __restrict__ Kg,
                    const float* __restrict__ Vg,
                    const float* __restrict__ Mg,
                    float* __restrict__ deAtt,
                    float* __restrict__ attnOut,
                    int nbh)
{
    __shared__ float lds[4 * WREG];   // 8 KB/block

    const int wv   = threadIdx.x >> 6;
    const int lane = threadIdx.x & 63;
    const int bh   = blockIdx.x * 4 + wv;
    if (bh >= nbh) return;            // no block barriers exist below

    float* sS    = lds + wv * WREG;   // [20][SSTR]
    float* sRinv = sS + SEQ * SSTR;   // [20]

    const size_t base = (size_t)bh * (SEQ * DK);
    const float4* gq = reinterpret_cast<const float4*>(Qg + base);
    const float4* gk = reinterpret_cast<const float4*>(Kg + base);
    const float4* gv = reinterpret_cast<const float4*>(Vg + base);
    const float*  m  = Mg + (size_t)bh * (SEQ * SEQ);

    // ---------- Phase B: exp-scores * mask; 4q x 2k tiles, lanes 0..49 ----------
    if (lane < 50) {
        const int qt = lane / 10;          // 0..4  -> q rows 4qt..4qt+3
        const int kt = lane - qt * 10;     // 0..9  -> k cols 2kt, 2kt+1
        const int q0 = qt * 4, k0 = kt * 2;
        float a[4][2] = {};
        #pragma unroll 2                   // 12 loads in flight; keeps VGPR < 64
        for (int g = 0; g < 16; ++g) {
            const float4 ka = gk[(k0    ) * 16 + g];
            const float4 kb = gk[(k0 + 1) * 16 + g];
            const float4 q0v = gq[(q0 + 0) * 16 + g];
            const float4 q1v = gq[(q0 + 1) * 16 + g];
            const float4 q2v = gq[(q0 + 2) * 16 + g];
            const float4 q3v = gq[(q0 + 3) * 16 + g];
            a[0][0] += q0v.x*ka.x + q0v.y*ka.y + q0v.z*ka.z + q0v.w*ka.w;
            a[0][1] += q0v.x*kb.x + q0v.y*kb.y + q0v.z*kb.z + q0v.w*kb.w;
            a[1][0] += q1v.x*ka.x + q1v.y*ka.y + q1v.z*ka.z + q1v.w*ka.w;
            a[1][1] += q1v.x*kb.x + q1v.y*kb.y + q1v.z*kb.z + q1v.w*kb.w;
            a[2][0] += q2v.x*ka.x + q2v.y*ka.y + q2v.z*ka.z + q2v.w*ka.w;
            a[2][1] += q2v.x*kb.x + q2v.y*kb.y + q2v.z*kb.z + q2v.w*kb.w;
            a[3][0] += q3v.x*ka.x + q3v.y*ka.y + q3v.z*ka.z + q3v.w*ka.w;
            a[3][1] += q3v.x*kb.x + q3v.y*kb.y + q3v.z*kb.z + q3v.w*kb.w;
        }
        #pragma unroll
        for (int i = 0; i < 4; ++i) {
            const float2 mm = *reinterpret_cast<const float2*>(m + (q0 + i) * SEQ + k0);
            float2 e;
            e.x = __expf(a[i][0] * 0.125f) * mm.x;
            e.y = __expf(a[i][1] * 0.125f) * mm.y;
            *reinterpret_cast<float2*>(sS + (q0 + i) * SSTR + k0) = e;
        }
    }
    wave_sync_lds();

    // ---------- Phase C: row sums -> 1/(sum+eps); lanes 0..19 ----------
    if (lane < SEQ) {
        const float4* row = reinterpret_cast<const float4*>(sS + lane * SSTR);
        const float4 r0 = row[0], r1 = row[1], r2 = row[2], r3 = row[3], r4 = row[4];
        const float s = r0.x + r0.y + r0.z + r0.w
                      + r1.x + r1.y + r1.z + r1.w
                      + r2.x + r2.y + r2.z + r2.w
                      + r3.x + r3.y + r3.z + r3.w
                      + r4.x + r4.y + r4.z + r4.w;
        sRinv[lane] = 1.0f / (s + 1e-8f);
    }
    wave_sync_lds();

    // ---------- Phase D: write normalized attn (100 float4 per bh) ----------
    {
        float4* aout = reinterpret_cast<float4*>(attnOut + (size_t)bh * (SEQ * SEQ));
        #pragma unroll
        for (int r = 0; r < 2; ++r) {
            const int idx = lane + r * 64;
            if (idx < 100) {
                const int q  = idx / 5;
                const int g4 = idx - q * 5;
                const float4 s = *reinterpret_cast<const float4*>(sS + q * SSTR + g4 * 4);
                const float rv = sRinv[q];
                aout[idx] = make_float4(s.x * rv, s.y * rv, s.z * rv, s.w * rv);
            }
        }
    }

    // ---------- Phase E: deAtt = (attn + Md) @ V; 64 lanes (qp, dg) ----------
    {
        const int qp = lane >> 4;        // 0..3 -> q rows qp*5 .. qp*5+4
        const int dg = lane & 15;        // output float4 column group
        float rv[5];
        #pragma unroll
        for (int j = 0; j < 5; ++j) rv[j] = sRinv[qp * 5 + j];

        float4 acc[5];
        #pragma unroll
        for (int j = 0; j < 5; ++j) acc[j] = make_float4(0.f, 0.f, 0.f, 0.f);

        #pragma unroll
        for (int k4 = 0; k4 < 5; ++k4) {
            const int kb = k4 * 4;
            const float4 v0 = gv[(kb + 0) * 16 + dg];   // V straight from global:
            const float4 v1 = gv[(kb + 1) * 16 + dg];   // read once, 256 B/instr
            const float4 v2 = gv[(kb + 2) * 16 + dg];
            const float4 v3 = gv[(kb + 3) * 16 + dg];
            const float kf0 = (float)(kb + 0), kf1 = (float)(kb + 1);
            const float kf2 = (float)(kb + 2), kf3 = (float)(kb + 3);
            #pragma unroll
            for (int j = 0; j < 5; ++j) {
                const int q = qp * 5 + j;
                const float qf = (float)q;
                const float4 s = *reinterpret_cast<const float4*>(sS + q * SSTR + kb);
                const float w0 = fmaf(s.x, rv[j], -fabsf(qf - kf0));
                const float w1 = fmaf(s.y, rv[j], -fabsf(qf - kf1));
                const float w2 = fmaf(s.z, rv[j], -fabsf(qf - kf2));
                const float w3 = fmaf(s.w, rv[j], -fabsf(qf - kf3));
                acc[j].x += w0 * v0.x + w1 * v1.x + w2 * v2.x + w3 * v3.x;
                acc[j].y += w0 * v0.y + w1 * v1.y + w2 * v2.y + w3 * v3.y;
                acc[j].z += w0 * v0.z + w1 * v1.z + w2 * v2.z + w3 * v3.z;
                acc[j].w += w0 * v0.w + w1 * v1.w + w2 * v2.w + w3 * v3.w;
            }
        }
        #pragma unroll
        for (int j = 0; j < 5; ++j) {
            const int q = qp * 5 + j;
            reinterpret_cast<float4*>(deAtt + base + q * DK)[dg] = acc[j];
        }
    }
}

extern "C" void kernel_launch(void* const* d_in, const int* in_sizes, int n_in,
                              void* d_out, int out_size, void* d_ws, size_t ws_size,
                              hipStream_t stream) {
    const float* Q = (const float*)d_in[0];
    const float* K = (const float*)d_in[1];
    const float* V = (const float*)d_in[2];
    const float* M = (const float*)d_in[3];
    float* out = (float*)d_out;

    const int nbh = in_sizes[0] / (SEQ * DK);        // B*H = 8192
    float* deAtt = out;                              // [nbh, SEQ, DK]
    float* attn  = out + (size_t)nbh * SEQ * DK;     // [nbh, SEQ, SEQ]

    const int blocks = (nbh + 3) / 4;
    fused_deatt_v3<<<blocks, 256, 0, stream>>>(Q, K, V, M, deAtt, attn, nbh);
}